// Round 6
// baseline (305.649 us; speedup 1.0000x reference)
//
#include <hip/hip_runtime.h>
#include <math.h>

#define BB  16
#define TT  12
#define T2C 10
#define NN  300
#define DD  64
#define M3  900   // 3*NN
#define NW  (BB*T2C)

typedef _Float16 f16;
typedef __attribute__((ext_vector_type(8)))  _Float16 f16x8;
typedef __attribute__((ext_vector_type(16))) float    f32x16;

#define KS 72   // fp16 row stride (144 B)

static __device__ inline unsigned pk2(f16 a, f16 b) {
    union { f16 h[2]; unsigned u; } x; x.h[0] = a; x.h[1] = b; return x.u;
}
static __device__ inline unsigned pk2f(float a, float b) {
    return pk2((f16)a, (f16)b);
}

// ---------------------------------------------------------------------------
// k_prep: blk < 960: fused norm + per-timestep ksum basis.
//         blk == 960: w1/w2 -> MFMA A-fragment order (fp16) in global.
// ---------------------------------------------------------------------------
__global__ __launch_bounds__(256) void k_prep(const float* __restrict__ feat,
                                              const float* __restrict__ weights,
                                              const float* __restrict__ w1,
                                              const float* __restrict__ w2,
                                              float* __restrict__ sigw,
                                              float* __restrict__ invn,
                                              float* __restrict__ tsum,
                                              f16* __restrict__ w1f,
                                              f16* __restrict__ w2f) {
    __shared__ float part[4][DD];
    int blk = blockIdx.x;
    int tid = threadIdx.x;

    if (blk == BB * TT * 5) {
        for (int p = tid; p < 1024; p += 256) {
            int lane = p & 63, s = p >> 6;
            int mat = s >> 3, loc = s & 7, ct = loc >> 2, ks = loc & 3;
            int hcol = ct * 32 + (lane & 31);
            const float* w = mat ? w2 : w1;
            f16* dst = (mat ? w2f : w1f) + ((size_t)loc * 64 + lane) * 8;
            f16x8 v;
            #pragma unroll
            for (int j = 0; j < 8; j++) {
                int d = ks * 16 + 8 * (lane >> 5) + j;
                v[j] = (f16)w[d * DD + hcol];
            }
            *(f16x8*)dst = v;
        }
        return;
    }

    int bt = blk / 5, ch = blk % 5;
    int row0 = bt * NN + ch * 60;
    int d = tid & 63, w = tid >> 6;

    float sg = 1.0f / (1.0f + expf(-weights[d]));
    if (blk == 0 && tid < 64) sigw[d] = sg;

    float acc = 0.f;
    for (int i = w; i < 60; i += 4) {
        int gr = row0 + i;
        float f = feat[(size_t)gr * DD + d];
        float x = f * sg;
        float ss = x * x;
        #pragma unroll
        for (int off = 32; off > 0; off >>= 1) ss += __shfl_xor(ss, off, 64);
        float in = 1.0f / fmaxf(sqrtf(ss), 1e-12f);
        if (d == 0) invn[gr] = in;
        acc += f * in;
    }
    part[w][d] = acc;
    __syncthreads();
    if (w == 0) {
        float v = (part[0][d] + part[1][d] + part[2][d] + part[3][d]) * sg;
        atomicAdd(&tsum[(size_t)bt * DD + d], v);
    }
}

// ---------------------------------------------------------------------------
// k_fused: aggregation (15 kt tiles, 2 barriers each, S via shfl_xor(32) -
// no S LDS) + in-LDS agg handoff + FFN (w frags pre-transposed in global) +
// residual + LayerNorm. One global write: final out.
// Block = (window wdw, 64-row tile rb); XCD swizzle: rb = blk/160.
// ---------------------------------------------------------------------------
__global__ __launch_bounds__(256) void k_fused(const float* __restrict__ feat,
                                               const float* __restrict__ sigw,
                                               const float* __restrict__ invn,
                                               const float* __restrict__ tsum,
                                               const f16* __restrict__ w1f,
                                               const f16* __restrict__ w2f,
                                               const float* __restrict__ b1,
                                               const float* __restrict__ b2,
                                               const float* __restrict__ gamma,
                                               const float* __restrict__ beta,
                                               float* __restrict__ out) {
    __shared__ union __align__(16) {
        struct { f16 Ft[64 * KS]; f16 Vt[64 * KS]; } a;   // kt-loop tiles
        float Ol[64 * 68];                                 // FFN stage (17.4KB<=18.4KB)
    } U;
    __shared__ __align__(16) f16 Hl[64 * KS];
    __shared__ float degp[64][4];
    __shared__ float degs[64];
    __shared__ float red[64][4][2];
    __shared__ float rmax[64][4];
    __shared__ float scls[64];
    __shared__ float isls[64];

    int blk = blockIdx.x;
    int wdw = blk % NW;    // swizzle: window's 5 blocks are 160 apart -> same XCD
    int rb  = blk / NW;
    int t2 = wdw % T2C, b = wdw / T2C;
    int n0 = rb * 64;
    int qrow0 = (b * TT + t2 + 2) * NN;
    int krow0 = (b * TT + t2) * NN;
    int tid = threadIdx.x;
    int wv = tid >> 6, lane = tid & 63;
    int l31 = lane & 31, lh = lane >> 5;
    int nt = wv & 1;    // n-block of this wave
    int dt = wv >> 1;   // d-block of this wave

    // ---- deg partials (fp32 tsum basis) ----
    {
        int r = tid >> 2, qd = (tid & 3) * 16;
        float p = 0.f;
        if (n0 + r < NN) {
            int gr = qrow0 + n0 + r;
            float in = invn[gr];
            const float4* f4 = (const float4*)(feat + (size_t)gr * DD + qd);
            const float4* s4 = (const float4*)(sigw + qd);
            const float4* t4 = (const float4*)(tsum + (size_t)(b * TT + t2) * DD + qd);
            #pragma unroll
            for (int i = 0; i < 4; i++) {
                float4 f = f4[i], s = s4[i];
                float4 k0 = t4[i], k1 = t4[i + 16], k2 = t4[i + 32];
                p += f.x * s.x * (k0.x + k1.x + k2.x) + f.y * s.y * (k0.y + k1.y + k2.y)
                   + f.z * s.z * (k0.z + k1.z + k2.z) + f.w * s.w * (k0.w + k1.w + k2.w);
            }
            p *= in;
        }
        degp[r][tid & 3] = p;
    }

    // ---- Q'' B-frags: feat_q * sigw^2 * invn_q ----
    f16x8 qf[4];
    {
        int nloc = n0 + nt * 32 + l31;
        bool ok = nloc < NN;
        int gr = qrow0 + (ok ? nloc : 0);
        float in = ok ? invn[gr] : 0.f;
        #pragma unroll
        for (int ks = 0; ks < 4; ks++) {
            int c0 = ks * 16 + 8 * lh;
            float4 f0 = *(const float4*)(feat + (size_t)gr * DD + c0);
            float4 f1 = *(const float4*)(feat + (size_t)gr * DD + c0 + 4);
            float4 s0 = *(const float4*)(sigw + c0);
            float4 s1 = *(const float4*)(sigw + c0 + 4);
            f16x8 qv;
            qv[0] = (f16)(f0.x * s0.x * s0.x * in); qv[1] = (f16)(f0.y * s0.y * s0.y * in);
            qv[2] = (f16)(f0.z * s0.z * s0.z * in); qv[3] = (f16)(f0.w * s0.w * s0.w * in);
            qv[4] = (f16)(f1.x * s1.x * s1.x * in); qv[5] = (f16)(f1.y * s1.y * s1.y * in);
            qv[6] = (f16)(f1.z * s1.z * s1.z * in); qv[7] = (f16)(f1.w * s1.w * s1.w * in);
            qf[ks] = qv;
        }
    }

    int mr = (tid & 31) * 2;     // staging: 2 m-rows
    int db = (tid >> 5) * 8;     // 8 d-cols

    float4 A0, A1, B0, B1;
    float i0, i1;
    {
        int g0 = krow0 + mr;
        A0 = *(const float4*)(feat + (size_t)g0 * DD + db);
        A1 = *(const float4*)(feat + (size_t)g0 * DD + db + 4);
        B0 = *(const float4*)(feat + (size_t)(g0 + 1) * DD + db);
        B1 = *(const float4*)(feat + (size_t)(g0 + 1) * DD + db + 4);
        i0 = invn[g0]; i1 = invn[g0 + 1];
    }
    {
        f16x8 r0, r1;
        r0[0]=(f16)A0.x; r0[1]=(f16)A0.y; r0[2]=(f16)A0.z; r0[3]=(f16)A0.w;
        r0[4]=(f16)A1.x; r0[5]=(f16)A1.y; r0[6]=(f16)A1.z; r0[7]=(f16)A1.w;
        r1[0]=(f16)B0.x; r1[1]=(f16)B0.y; r1[2]=(f16)B0.z; r1[3]=(f16)B0.w;
        r1[4]=(f16)B1.x; r1[5]=(f16)B1.y; r1[6]=(f16)B1.z; r1[7]=(f16)B1.w;
        *(f16x8*)&U.a.Ft[mr * KS + db] = r0;
        *(f16x8*)&U.a.Ft[(mr + 1) * KS + db] = r1;
        float a[8] = {A0.x, A0.y, A0.z, A0.w, A1.x, A1.y, A1.z, A1.w};
        float c[8] = {B0.x, B0.y, B0.z, B0.w, B1.x, B1.y, B1.z, B1.w};
        #pragma unroll
        for (int i = 0; i < 8; i++)
            *(unsigned*)&U.a.Vt[(db + i) * KS + mr] = pk2f(a[i] * i0, c[i] * i1);
    }
    __syncthreads();
    if (tid < 64)
        degs[tid] = degp[tid][0] + degp[tid][1] + degp[tid][2] + degp[tid][3];

    f32x16 acc;
    #pragma unroll
    for (int i = 0; i < 16; i++) acc[i] = 0.f;

    for (int kt = 0; kt < 15; kt++) {
        bool has_next = kt < 14;
        if (has_next) {
            int m0n = (kt + 1) * 64;
            int gm0 = m0n + mr, gm1 = gm0 + 1;
            bool ok0 = gm0 < M3, ok1 = gm1 < M3;
            int g0 = krow0 + (ok0 ? gm0 : 0);
            int g1 = krow0 + (ok1 ? gm1 : 0);
            A0 = *(const float4*)(feat + (size_t)g0 * DD + db);
            A1 = *(const float4*)(feat + (size_t)g0 * DD + db + 4);
            B0 = *(const float4*)(feat + (size_t)g1 * DD + db);
            B1 = *(const float4*)(feat + (size_t)g1 * DD + db + 4);
            i0 = ok0 ? invn[g0] : 0.f;
            i1 = ok1 ? invn[g1] : 0.f;
            if (!ok0) { A0 = make_float4(0,0,0,0); A1 = A0; }
            if (!ok1) { B0 = make_float4(0,0,0,0); B1 = B0; }
        }

        // ---- phase1: S'' rows for this wave's n-block (m = 0..63) ----
        f32x16 c1a, c1b;
        #pragma unroll
        for (int i = 0; i < 16; i++) { c1a[i] = 0.f; c1b[i] = 0.f; }
        #pragma unroll
        for (int ks = 0; ks < 4; ks++) {
            f16x8 af0 = *(const f16x8*)&U.a.Ft[l31 * KS + ks * 16 + 8 * lh];
            f16x8 af1 = *(const f16x8*)&U.a.Ft[(32 + l31) * KS + ks * 16 + 8 * lh];
            c1a = __builtin_amdgcn_mfma_f32_32x32x16_f16(af0, qf[ks], c1a, 0, 0, 0);
            c1b = __builtin_amdgcn_mfma_f32_32x32x16_f16(af1, qf[ks], c1b, 0, 0, 0);
        }
        // ---- S C-layout -> A-frags via lane^32 exchange (no LDS) ----
        #pragma unroll
        for (int ms = 0; ms < 4; ms++) {
            f32x16 ch = (ms < 2) ? c1a : c1b;
            int g_own  = 2 * (ms & 1) + lh;
            int g_send = 2 * (ms & 1) + (1 - lh);
            unsigned o0 = pk2f(ch[4*g_own+0],  ch[4*g_own+1]);
            unsigned o1 = pk2f(ch[4*g_own+2],  ch[4*g_own+3]);
            unsigned s0 = pk2f(ch[4*g_send+0], ch[4*g_send+1]);
            unsigned s1 = pk2f(ch[4*g_send+2], ch[4*g_send+3]);
            unsigned r0 = (unsigned)__shfl_xor((int)s0, 32, 64);
            unsigned r1 = (unsigned)__shfl_xor((int)s1, 32, 64);
            union { unsigned u[4]; f16x8 v; } sa;
            if (lh == 0) { sa.u[0]=o0; sa.u[1]=o1; sa.u[2]=r0; sa.u[3]=r1; }
            else         { sa.u[0]=r0; sa.u[1]=r1; sa.u[2]=o0; sa.u[3]=o1; }
            f16x8 vb = *(const f16x8*)&U.a.Vt[(dt * 32 + l31) * KS + ms * 16 + 8 * lh];
            acc = __builtin_amdgcn_mfma_f32_32x32x16_f16(sa.v, vb, acc, 0, 0, 0);
        }
        __syncthreads();   // all reads of Ft/Vt done
        if (has_next) {
            f16x8 r0, r1;
            r0[0]=(f16)A0.x; r0[1]=(f16)A0.y; r0[2]=(f16)A0.z; r0[3]=(f16)A0.w;
            r0[4]=(f16)A1.x; r0[5]=(f16)A1.y; r0[6]=(f16)A1.z; r0[7]=(f16)A1.w;
            r1[0]=(f16)B0.x; r1[1]=(f16)B0.y; r1[2]=(f16)B0.z; r1[3]=(f16)B0.w;
            r1[4]=(f16)B1.x; r1[5]=(f16)B1.y; r1[6]=(f16)B1.z; r1[7]=(f16)B1.w;
            *(f16x8*)&U.a.Ft[mr * KS + db] = r0;
            *(f16x8*)&U.a.Ft[(mr + 1) * KS + db] = r1;
            float a[8] = {A0.x, A0.y, A0.z, A0.w, A1.x, A1.y, A1.z, A1.w};
            float c[8] = {B0.x, B0.y, B0.z, B0.w, B1.x, B1.y, B1.z, B1.w};
            #pragma unroll
            for (int i = 0; i < 8; i++)
                *(unsigned*)&U.a.Vt[(db + i) * KS + mr] = pk2f(a[i] * i0, c[i] * i1);
        }
        __syncthreads();
    }

    // ================= FFN stage (LDS handoff, no agg global round-trip) ====
    __builtin_amdgcn_sched_barrier(0);
    int ct = wv & 1, rt = wv >> 1;
    f16x8 w1a[4], w2a[4];
    #pragma unroll
    for (int ks = 0; ks < 4; ks++) {
        w1a[ks] = *(const f16x8*)(w1f + ((size_t)(ct * 4 + ks) * 64 + lane) * 8);
        w2a[ks] = *(const f16x8*)(w2f + ((size_t)(ct * 4 + ks) * 64 + lane) * 8);
    }
    __syncthreads();   // kt loop fully done; union switches to Ol

    // agg = acc * dinv -> Ol[row][col] fp32
    {
        int dcol = dt * 32 + l31;
        #pragma unroll
        for (int g = 0; g < 4; g++) {
            #pragma unroll
            for (int i = 0; i < 4; i++) {
                int rl = nt * 32 + 8 * g + 4 * lh + i;
                float dg = degs[rl];
                float dinv = (dg == 0.f) ? 0.f : 1.f / dg;
                U.Ol[rl * 68 + dcol] = acc[4 * g + i] * dinv;
            }
        }
    }
    __syncthreads();

    int r = tid >> 2, q = tid & 3, c0 = q * 16;
    {
        float mx = 0.f;
        #pragma unroll
        for (int i = 0; i < 16; i += 4) {
            float4 f = *(const float4*)&U.Ol[r * 68 + c0 + i];
            mx = fmaxf(mx, fmaxf(fmaxf(fabsf(f.x), fabsf(f.y)),
                                 fmaxf(fabsf(f.z), fabsf(f.w))));
        }
        rmax[r][q] = mx;
    }
    __syncthreads();
    if (q == 0) {
        float rm = fmaxf(fmaxf(rmax[r][0], rmax[r][1]), fmaxf(rmax[r][2], rmax[r][3]));
        int e = 0;
        frexpf(rm, &e);
        scls[r] = (rm > 1.f) ? exp2f((float)-e) : 1.f;
        isls[r] = (rm > 1.f) ? exp2f((float)e) : 1.f;
    }
    __syncthreads();

    // phase A: h_s^T = w1^T . A_s^T  (A_s read from Ol, scaled on the fly)
    float sclrow = scls[rt * 32 + l31];
    f32x16 hc;
    #pragma unroll
    for (int i = 0; i < 16; i++) hc[i] = 0.f;
    #pragma unroll
    for (int ks = 0; ks < 4; ks++) {
        const float* prow = &U.Ol[(rt * 32 + l31) * 68 + ks * 16 + 8 * lh];
        float4 pa = *(const float4*)prow;
        float4 pb = *(const float4*)(prow + 4);
        f16x8 bf;
        bf[0] = (f16)(pa.x * sclrow); bf[1] = (f16)(pa.y * sclrow);
        bf[2] = (f16)(pa.z * sclrow); bf[3] = (f16)(pa.w * sclrow);
        bf[4] = (f16)(pb.x * sclrow); bf[5] = (f16)(pb.y * sclrow);
        bf[6] = (f16)(pb.z * sclrow); bf[7] = (f16)(pb.w * sclrow);
        hc = __builtin_amdgcn_mfma_f32_32x32x16_f16(w1a[ks], bf, hc, 0, 0, 0);
    }
    {
        float sA = sclrow;
        #pragma unroll
        for (int g = 0; g < 4; g++) {
            union { f16 h[4]; uint2 u; } p;
            #pragma unroll
            for (int i = 0; i < 4; i++) {
                int hcol = ct * 32 + 8 * g + 4 * lh + i;
                p.h[i] = (f16)fmaxf(hc[4 * g + i] + sA * b1[hcol], 0.f);
            }
            *(uint2*)&Hl[(rt * 32 + l31) * KS + ct * 32 + 8 * g + 4 * lh] = p.u;
        }
    }
    __syncthreads();

    // phase B: o_s^T = w2^T . h_s^T ; result overwrites Ol (agg dead)
    f32x16 oc;
    #pragma unroll
    for (int i = 0; i < 16; i++) oc[i] = 0.f;
    #pragma unroll
    for (int ks = 0; ks < 4; ks++) {
        f16x8 bf = *(const f16x8*)&Hl[(rt * 32 + l31) * KS + ks * 16 + 8 * lh];
        oc = __builtin_amdgcn_mfma_f32_32x32x16_f16(w2a[ks], bf, oc, 0, 0, 0);
    }
    __syncthreads();   // everyone's phase-A Ol reads are long done; safe to overwrite
    #pragma unroll
    for (int g = 0; g < 4; g++) {
        float4 o4 = make_float4(oc[4*g+0], oc[4*g+1], oc[4*g+2], oc[4*g+3]);
        *(float4*)&U.Ol[(rt * 32 + l31) * 68 + ct * 32 + 8 * g + 4 * lh] = o4;
    }
    __syncthreads();

    // epilogue: s = o_s/s_n + b2 + residual; LayerNorm; guarded store
    int n = n0 + r;
    int nn = (n < NN) ? n : (NN - 1);
    size_t frow = (size_t)(b * TT + t2 + 2) * NN + nn;
    float is = isls[r];
    float v[16];
    float sum = 0.f;
    #pragma unroll
    for (int i = 0; i < 16; i++) {
        int c = c0 + i;
        float x = U.Ol[r * 68 + c] * is + b2[c] + feat[frow * DD + c];
        v[i] = x; sum += x;
    }
    red[r][q][0] = sum;
    __syncthreads();
    float mu = (red[r][0][0] + red[r][1][0] + red[r][2][0] + red[r][3][0]) * (1.f / 64.f);
    float s2 = 0.f;
    #pragma unroll
    for (int i = 0; i < 16; i++) { float d = v[i] - mu; s2 += d * d; }
    red[r][q][1] = s2;
    __syncthreads();
    float var = (red[r][0][1] + red[r][1][1] + red[r][2][1] + red[r][3][1]) * (1.f / 64.f);
    float rs = rsqrtf(var + 1e-5f);
    if (n < NN) {
        size_t grow = (size_t)(b * T2C + t2) * NN + n;
        #pragma unroll
        for (int i4 = 0; i4 < 4; i4++) {
            int c = c0 + 4 * i4;
            float4 g4 = *(const float4*)(gamma + c);
            float4 be = *(const float4*)(beta + c);
            float4 o4;
            o4.x = (v[4*i4+0] - mu) * rs * g4.x + be.x;
            o4.y = (v[4*i4+1] - mu) * rs * g4.y + be.y;
            o4.z = (v[4*i4+2] - mu) * rs * g4.z + be.z;
            o4.w = (v[4*i4+3] - mu) * rs * g4.w + be.w;
            *(float4*)(out + grow * DD + c) = o4;
        }
    }
}

// ---------------------------------------------------------------------------
extern "C" void kernel_launch(void* const* d_in, const int* in_sizes, int n_in,
                              void* d_out, int out_size, void* d_ws, size_t ws_size,
                              hipStream_t stream) {
    const float* feat    = (const float*)d_in[0];
    const float* weights = (const float*)d_in[1];
    const float* w1      = (const float*)d_in[2];
    const float* b1      = (const float*)d_in[3];
    const float* w2      = (const float*)d_in[4];
    const float* b2      = (const float*)d_in[5];
    const float* gamma   = (const float*)d_in[6];
    const float* beta    = (const float*)d_in[7];
    float* out = (float*)d_out;

    float* sigw = (float*)d_ws;                 // 64
    float* invn = sigw + 64;                    // 57600
    float* tsum = invn + BB * TT * NN;          // 12288
    f16*   w1f  = (f16*)(tsum + BB * TT * DD);  // 4096 f16
    f16*   w2f  = w1f + 4096;                   // 4096 f16

    hipMemsetAsync(tsum, 0, (size_t)BB * TT * DD * sizeof(float), stream);
    k_prep<<<BB * TT * 5 + 1, 256, 0, stream>>>(feat, weights, w1, w2,
                                                sigw, invn, tsum, w1f, w2f);
    k_fused<<<NW * 5, 256, 0, stream>>>(feat, sigw, invn, tsum, w1f, w2f,
                                        b1, b2, gamma, beta, out);
}

// Round 7
// 136.924 us; speedup vs baseline: 2.2323x; 2.2323x over previous
//
#include <hip/hip_runtime.h>
#include <math.h>

#define BB  16
#define TT  12
#define T2C 10
#define NN  300
#define DD  64
#define M3  900   // 3*NN
#define NW  (BB*T2C)

typedef _Float16 f16;
typedef __attribute__((ext_vector_type(8)))  _Float16 f16x8;
typedef __attribute__((ext_vector_type(16))) float    f32x16;

#define KS 72   // fp16 row stride (144 B)

static __device__ inline unsigned pk2(f16 a, f16 b) {
    union { f16 h[2]; unsigned u; } x; x.h[0] = a; x.h[1] = b; return x.u;
}

// ---------------------------------------------------------------------------
// k_prep: blk < 960: fused norm + per-timestep ksum basis.
//         blk == 960: w1/w2 -> MFMA A-fragment order (fp16) in global.
// ---------------------------------------------------------------------------
__global__ __launch_bounds__(256) void k_prep(const float* __restrict__ feat,
                                              const float* __restrict__ weights,
                                              const float* __restrict__ w1,
                                              const float* __restrict__ w2,
                                              float* __restrict__ sigw,
                                              float* __restrict__ invn,
                                              float* __restrict__ tsum,
                                              f16* __restrict__ w1f,
                                              f16* __restrict__ w2f) {
    __shared__ float part[4][DD];
    int blk = blockIdx.x;
    int tid = threadIdx.x;

    if (blk == BB * TT * 5) {
        for (int p = tid; p < 1024; p += 256) {
            int lane = p & 63, s = p >> 6;
            int mat = s >> 3, loc = s & 7, ct = loc >> 2, ks = loc & 3;
            int hcol = ct * 32 + (lane & 31);
            const float* w = mat ? w2 : w1;
            f16* dst = (mat ? w2f : w1f) + ((size_t)loc * 64 + lane) * 8;
            f16x8 v;
            #pragma unroll
            for (int j = 0; j < 8; j++) {
                int d = ks * 16 + 8 * (lane >> 5) + j;
                v[j] = (f16)w[d * DD + hcol];
            }
            *(f16x8*)dst = v;
        }
        return;
    }

    int bt = blk / 5, ch = blk % 5;
    int row0 = bt * NN + ch * 60;
    int d = tid & 63, w = tid >> 6;

    float sg = 1.0f / (1.0f + expf(-weights[d]));
    if (blk == 0 && tid < 64) sigw[d] = sg;

    float acc = 0.f;
    for (int i = w; i < 60; i += 4) {
        int gr = row0 + i;
        float f = feat[(size_t)gr * DD + d];
        float x = f * sg;
        float ss = x * x;
        #pragma unroll
        for (int off = 32; off > 0; off >>= 1) ss += __shfl_xor(ss, off, 64);
        float in = 1.0f / fmaxf(sqrtf(ss), 1e-12f);
        if (d == 0) invn[gr] = in;
        acc += f * in;
    }
    part[w][d] = acc;
    __syncthreads();
    if (w == 0) {
        float v = (part[0][d] + part[1][d] + part[2][d] + part[3][d]) * sg;
        atomicAdd(&tsum[(size_t)bt * DD + d], v);
    }
}

// ---------------------------------------------------------------------------
// k_fused = r4 k_agg loop (S through LDS, 3 barriers/kt — measured-best)
//         + fused FFN/LayerNorm tail (no agg global round-trip)
//         + XCD swizzle (window's 5 blocks 160 apart -> same XCD).
// ---------------------------------------------------------------------------
__global__ __launch_bounds__(256) void k_fused(const float* __restrict__ feat,
                                               const float* __restrict__ sigw,
                                               const float* __restrict__ invn,
                                               const float* __restrict__ tsum,
                                               const f16* __restrict__ w1f,
                                               const f16* __restrict__ w2f,
                                               const float* __restrict__ b1,
                                               const float* __restrict__ b2,
                                               const float* __restrict__ gamma,
                                               const float* __restrict__ beta,
                                               float* __restrict__ out) {
    __shared__ union __align__(16) {
        struct __align__(16) {              // aggregation stage (28.7 KB)
            f16 Kf[64 * KS];
            f16 Vt[64 * KS];
            f16 Sl[64 * KS];
            float degp[64][4];
        } a;
        struct __align__(16) {              // FFN stage (30.2 KB)
            float Ol[64 * 68];
            f16 Hl[64 * KS];
            float red[64][4][2];
            float rmax[64][4];
            float scls[64];
            float isls[64];
        } b;
    } U;
    __shared__ float degs[64];

    int blk = blockIdx.x;
    int wdw = blk % NW;
    int rb  = blk / NW;
    int t2 = wdw % T2C, b = wdw / T2C;
    int n0 = rb * 64;
    int qrow0 = (b * TT + t2 + 2) * NN;
    int krow0 = (b * TT + t2) * NN;
    int tid = threadIdx.x;
    int wv = tid >> 6, lane = tid & 63;
    int l31 = lane & 31, lh = lane >> 5;
    int nt = wv & 1;   // phase1 n-block == phase2 row-block
    int mt = wv >> 1;  // phase1 m-tile  == phase2 d-block

    // ---- deg partials: deg[n] = (feat[n]*sigw . ksum_w) * invn[n] ----
    {
        int r = tid >> 2, qd = (tid & 3) * 16;
        float p = 0.f;
        if (n0 + r < NN) {
            int gr = qrow0 + n0 + r;
            float in = invn[gr];
            const float4* f4 = (const float4*)(feat + (size_t)gr * DD + qd);
            const float4* s4 = (const float4*)(sigw + qd);
            const float4* t4 = (const float4*)(tsum + (size_t)(b * TT + t2) * DD + qd);
            #pragma unroll
            for (int i = 0; i < 4; i++) {
                float4 f = f4[i], s = s4[i];
                float4 k0 = t4[i], k1 = t4[i + 16], k2 = t4[i + 32];
                p += f.x * s.x * (k0.x + k1.x + k2.x) + f.y * s.y * (k0.y + k1.y + k2.y)
                   + f.z * s.z * (k0.z + k1.z + k2.z) + f.w * s.w * (k0.w + k1.w + k2.w);
            }
            p *= in;
        }
        U.a.degp[r][tid & 3] = p;
    }

    // ---- Q'' B-frags in registers: feat_q * sigw^2 * invn_q ----
    f16x8 qf[4];
    {
        int nloc = n0 + nt * 32 + l31;
        bool ok = nloc < NN;
        int gr = qrow0 + (ok ? nloc : 0);
        float in = ok ? invn[gr] : 0.f;
        #pragma unroll
        for (int ks = 0; ks < 4; ks++) {
            int c0 = ks * 16 + 8 * lh;
            float4 f0 = *(const float4*)(feat + (size_t)gr * DD + c0);
            float4 f1 = *(const float4*)(feat + (size_t)gr * DD + c0 + 4);
            float4 s0 = *(const float4*)(sigw + c0);
            float4 s1 = *(const float4*)(sigw + c0 + 4);
            f16x8 qv;
            qv[0] = (f16)(f0.x * s0.x * s0.x * in); qv[1] = (f16)(f0.y * s0.y * s0.y * in);
            qv[2] = (f16)(f0.z * s0.z * s0.z * in); qv[3] = (f16)(f0.w * s0.w * s0.w * in);
            qv[4] = (f16)(f1.x * s1.x * s1.x * in); qv[5] = (f16)(f1.y * s1.y * s1.y * in);
            qv[6] = (f16)(f1.z * s1.z * s1.z * in); qv[7] = (f16)(f1.w * s1.w * s1.w * in);
            qf[ks] = qv;
        }
    }
    __syncthreads();
    if (tid < 64)
        degs[tid] = U.a.degp[tid][0] + U.a.degp[tid][1]
                  + U.a.degp[tid][2] + U.a.degp[tid][3];

    f32x16 acc;
    #pragma unroll
    for (int i = 0; i < 16; i++) acc[i] = 0.f;

    int mrow_s = (tid & 31) * 2;     // staging m-pair
    int dblk_s = (tid >> 5) * 8;     // staging 8-col block

    for (int kt = 0; kt < 15; kt++) {
        int m0 = kt * 64;
        __syncthreads();             // prev phase2 done with Vt/Sl

        // ---- stage Kf (feat*invn fp16, Vt-source values in regs) ----
        f16 vv[2][8];
        #pragma unroll
        for (int pi = 0; pi < 2; pi++) {
            int mloc = mrow_s + pi, gm = m0 + mloc;
            float4 fa = make_float4(0, 0, 0, 0), fb = make_float4(0, 0, 0, 0);
            float in = 0.f;
            if (gm < M3) {
                int gr = krow0 + gm;
                in = invn[gr];
                fa = *(const float4*)(feat + (size_t)gr * DD + dblk_s);
                fb = *(const float4*)(feat + (size_t)gr * DD + dblk_s + 4);
            }
            // K-row for phase1: raw feat (Q carries sigw^2*invn); V: feat*invn
            f16x8 kr;
            kr[0] = (f16)fa.x; kr[1] = (f16)fa.y; kr[2] = (f16)fa.z; kr[3] = (f16)fa.w;
            kr[4] = (f16)fb.x; kr[5] = (f16)fb.y; kr[6] = (f16)fb.z; kr[7] = (f16)fb.w;
            *(f16x8*)&U.a.Kf[mloc * KS + dblk_s] = kr;
            vv[pi][0] = (f16)(fa.x * in); vv[pi][1] = (f16)(fa.y * in);
            vv[pi][2] = (f16)(fa.z * in); vv[pi][3] = (f16)(fa.w * in);
            vv[pi][4] = (f16)(fb.x * in); vv[pi][5] = (f16)(fb.y * in);
            vv[pi][6] = (f16)(fb.z * in); vv[pi][7] = (f16)(fb.w * in);
        }
        __syncthreads();

        // ---- phase1: S''^T tile (m-rows mt*32.., n-cols nt*32..) ----
        f32x16 c1;
        #pragma unroll
        for (int i = 0; i < 16; i++) c1[i] = 0.f;
        #pragma unroll
        for (int ks = 0; ks < 4; ks++) {
            f16x8 af = *(const f16x8*)&U.a.Kf[(mt * 32 + l31) * KS + ks * 16 + 8 * lh];
            c1 = __builtin_amdgcn_mfma_f32_32x32x16_f16(af, qf[ks], c1, 0, 0, 0);
        }
        // write S_lds[n][m]: C rows are m-runs of 4 -> b64
        #pragma unroll
        for (int g = 0; g < 4; g++) {
            union { f16 h[4]; uint2 u; } p;
            p.h[0] = (f16)c1[4 * g + 0]; p.h[1] = (f16)c1[4 * g + 1];
            p.h[2] = (f16)c1[4 * g + 2]; p.h[3] = (f16)c1[4 * g + 3];
            *(uint2*)&U.a.Sl[(nt * 32 + l31) * KS + mt * 32 + 8 * g + 4 * lh] = p.u;
        }
        __syncthreads();             // K reads + St writes done

        // ---- stage Vt (feat*invn transposed) from regs ----
        #pragma unroll
        for (int i = 0; i < 8; i++)
            *(unsigned*)&U.a.Vt[(dblk_s + i) * KS + mrow_s] = pk2(vv[0][i], vv[1][i]);
        __syncthreads();

        // ---- phase2: acc(n-block nt, d-block mt) += S . V ----
        #pragma unroll
        for (int ms = 0; ms < 4; ms++) {
            f16x8 sa = *(const f16x8*)&U.a.Sl[(nt * 32 + l31) * KS + ms * 16 + 8 * lh];
            f16x8 vb = *(const f16x8*)&U.a.Vt[(mt * 32 + l31) * KS + ms * 16 + 8 * lh];
            acc = __builtin_amdgcn_mfma_f32_32x32x16_f16(sa, vb, acc, 0, 0, 0);
        }
    }
    __syncthreads();                 // agg stage done; union switches to FFN

    // ================= FFN stage (in-LDS handoff) ==========================
    int ct = wv & 1, rt = wv >> 1;
    f16x8 w1a[4], w2a[4];
    #pragma unroll
    for (int ks = 0; ks < 4; ks++) {
        w1a[ks] = *(const f16x8*)(w1f + ((size_t)(ct * 4 + ks) * 64 + lane) * 8);
        w2a[ks] = *(const f16x8*)(w2f + ((size_t)(ct * 4 + ks) * 64 + lane) * 8);
    }

    // agg = acc * dinv -> Ol[row][col] fp32
    {
        int dcol = mt * 32 + l31;
        #pragma unroll
        for (int g = 0; g < 4; g++) {
            #pragma unroll
            for (int i = 0; i < 4; i++) {
                int rl = nt * 32 + 8 * g + 4 * lh + i;
                float dg = degs[rl];
                float dinv = (dg == 0.f) ? 0.f : 1.f / dg;
                U.b.Ol[rl * 68 + dcol] = acc[4 * g + i] * dinv;
            }
        }
    }
    __syncthreads();

    int r = tid >> 2, q = tid & 3, c0 = q * 16;
    {
        float mx = 0.f;
        #pragma unroll
        for (int i = 0; i < 16; i += 4) {
            float4 f = *(const float4*)&U.b.Ol[r * 68 + c0 + i];
            mx = fmaxf(mx, fmaxf(fmaxf(fabsf(f.x), fabsf(f.y)),
                                 fmaxf(fabsf(f.z), fabsf(f.w))));
        }
        U.b.rmax[r][q] = mx;
    }
    __syncthreads();
    if (q == 0) {
        float rm = fmaxf(fmaxf(U.b.rmax[r][0], U.b.rmax[r][1]),
                         fmaxf(U.b.rmax[r][2], U.b.rmax[r][3]));
        int e = 0;
        frexpf(rm, &e);
        U.b.scls[r] = (rm > 1.f) ? exp2f((float)-e) : 1.f;
        U.b.isls[r] = (rm > 1.f) ? exp2f((float)e) : 1.f;
    }
    __syncthreads();

    // phase A: h_s^T = w1^T . A_s^T  (A_s read from Ol, scaled on the fly)
    float sclrow = U.b.scls[rt * 32 + l31];
    f32x16 hc;
    #pragma unroll
    for (int i = 0; i < 16; i++) hc[i] = 0.f;
    #pragma unroll
    for (int ks = 0; ks < 4; ks++) {
        const float* prow = &U.b.Ol[(rt * 32 + l31) * 68 + ks * 16 + 8 * lh];
        float4 pa = *(const float4*)prow;
        float4 pb = *(const float4*)(prow + 4);
        f16x8 bf;
        bf[0] = (f16)(pa.x * sclrow); bf[1] = (f16)(pa.y * sclrow);
        bf[2] = (f16)(pa.z * sclrow); bf[3] = (f16)(pa.w * sclrow);
        bf[4] = (f16)(pb.x * sclrow); bf[5] = (f16)(pb.y * sclrow);
        bf[6] = (f16)(pb.z * sclrow); bf[7] = (f16)(pb.w * sclrow);
        hc = __builtin_amdgcn_mfma_f32_32x32x16_f16(w1a[ks], bf, hc, 0, 0, 0);
    }
    #pragma unroll
    for (int g = 0; g < 4; g++) {
        union { f16 h[4]; uint2 u; } p;
        #pragma unroll
        for (int i = 0; i < 4; i++) {
            int hcol = ct * 32 + 8 * g + 4 * lh + i;
            p.h[i] = (f16)fmaxf(hc[4 * g + i] + sclrow * b1[hcol], 0.f);
        }
        *(uint2*)&U.b.Hl[(rt * 32 + l31) * KS + ct * 32 + 8 * g + 4 * lh] = p.u;
    }
    __syncthreads();

    // phase B: o_s^T = w2^T . h_s^T ; result overwrites Ol (agg dead)
    f32x16 oc;
    #pragma unroll
    for (int i = 0; i < 16; i++) oc[i] = 0.f;
    #pragma unroll
    for (int ks = 0; ks < 4; ks++) {
        f16x8 bf = *(const f16x8*)&U.b.Hl[(rt * 32 + l31) * KS + ks * 16 + 8 * lh];
        oc = __builtin_amdgcn_mfma_f32_32x32x16_f16(w2a[ks], bf, oc, 0, 0, 0);
    }
    __syncthreads();
    #pragma unroll
    for (int g = 0; g < 4; g++) {
        float4 o4 = make_float4(oc[4*g+0], oc[4*g+1], oc[4*g+2], oc[4*g+3]);
        *(float4*)&U.b.Ol[(rt * 32 + l31) * 68 + ct * 32 + 8 * g + 4 * lh] = o4;
    }
    __syncthreads();

    // epilogue: s = o_s/s_n + b2 + residual; LayerNorm; guarded store
    int n = n0 + r;
    int nn = (n < NN) ? n : (NN - 1);
    size_t frow = (size_t)(b * TT + t2 + 2) * NN + nn;
    float is = U.b.isls[r];
    float v[16];
    float sum = 0.f;
    #pragma unroll
    for (int i = 0; i < 16; i++) {
        int c = c0 + i;
        float x = U.b.Ol[r * 68 + c] * is + b2[c] + feat[frow * DD + c];
        v[i] = x; sum += x;
    }
    U.b.red[r][q][0] = sum;
    __syncthreads();
    float mu = (U.b.red[r][0][0] + U.b.red[r][1][0]
              + U.b.red[r][2][0] + U.b.red[r][3][0]) * (1.f / 64.f);
    float s2 = 0.f;
    #pragma unroll
    for (int i = 0; i < 16; i++) { float d = v[i] - mu; s2 += d * d; }
    U.b.red[r][q][1] = s2;
    __syncthreads();
    float var = (U.b.red[r][0][1] + U.b.red[r][1][1]
               + U.b.red[r][2][1] + U.b.red[r][3][1]) * (1.f / 64.f);
    float rs = rsqrtf(var + 1e-5f);
    if (n < NN) {
        size_t grow = (size_t)(b * T2C + t2) * NN + n;
        #pragma unroll
        for (int i4 = 0; i4 < 4; i4++) {
            int c = c0 + 4 * i4;
            float4 g4 = *(const float4*)(gamma + c);
            float4 be = *(const float4*)(beta + c);
            float4 o4;
            o4.x = (v[4*i4+0] - mu) * rs * g4.x + be.x;
            o4.y = (v[4*i4+1] - mu) * rs * g4.y + be.y;
            o4.z = (v[4*i4+2] - mu) * rs * g4.z + be.z;
            o4.w = (v[4*i4+3] - mu) * rs * g4.w + be.w;
            *(float4*)(out + grow * DD + c) = o4;
        }
    }
}

// ---------------------------------------------------------------------------
extern "C" void kernel_launch(void* const* d_in, const int* in_sizes, int n_in,
                              void* d_out, int out_size, void* d_ws, size_t ws_size,
                              hipStream_t stream) {
    const float* feat    = (const float*)d_in[0];
    const float* weights = (const float*)d_in[1];
    const float* w1      = (const float*)d_in[2];
    const float* b1      = (const float*)d_in[3];
    const float* w2      = (const float*)d_in[4];
    const float* b2      = (const float*)d_in[5];
    const float* gamma   = (const float*)d_in[6];
    const float* beta    = (const float*)d_in[7];
    float* out = (float*)d_out;

    float* sigw = (float*)d_ws;                 // 64
    float* invn = sigw + 64;                    // 57600
    float* tsum = invn + BB * TT * NN;          // 12288
    f16*   w1f  = (f16*)(tsum + BB * TT * DD);  // 4096 f16
    f16*   w2f  = w1f + 4096;                   // 4096 f16

    hipMemsetAsync(tsum, 0, (size_t)BB * TT * DD * sizeof(float), stream);
    k_prep<<<BB * TT * 5 + 1, 256, 0, stream>>>(feat, weights, w1, w2,
                                                sigw, invn, tsum, w1f, w2f);
    k_fused<<<NW * 5, 256, 0, stream>>>(feat, sigw, invn, tsum, w1f, w2f,
                                        b1, b2, gamma, beta, out);
}